// Round 2
// baseline (34317.337 us; speedup 1.0000x reference)
//
#include <hip/hip_runtime.h>

#define NB 128       // batch
#define NT 1024      // time steps
#define NH 256       // hidden
#define NL 2         // layers
#define NO 256       // output dim
#define G3 768       // 3*NH

// ws layout (floats):
// Wiht4: [l][k4][j][4] at 0        : l*196608 + k4*3072 + j*4 + c  (= W_ih[l][j][4k4+c])
// Whht4: [l][k4][j][4] at 393216
// Woutt4: [k4][o][4]   at 786432   : k4*1024 + o*4 + c             (= W_out[o][4k4+c])
#define WIHT_OFF 0
#define WHHT_OFF 393216
#define WOUT_OFF 786432

__global__ void prep_kernel(const float* __restrict__ Wih,
                            const float* __restrict__ Whh,
                            const float* __restrict__ Wout,
                            float* __restrict__ ws) {
  int idx = blockIdx.x * 256 + threadIdx.x;
  if (idx < 393216) {
    int c = idx & 3;
    int q = idx >> 2;          // (l*64+k4)*768 + j
    int j = q % 768;
    int lk4 = q / 768;         // l*64 + k4
    int k4 = lk4 & 63;
    int l = lk4 >> 6;
    size_t src = (size_t)(l * 768 + j) * 256 + k4 * 4 + c;
    ws[WIHT_OFF + idx] = Wih[src];
    ws[WHHT_OFF + idx] = Whh[src];
  }
  if (idx < 65536) {
    int c = idx & 3;
    int q = idx >> 2;
    int o = q & 255;
    int k4 = q >> 8;
    ws[WOUT_OFF + idx] = Wout[o * 256 + k4 * 4 + c];
  }
}

__device__ __forceinline__ float dot4(float4 a, float4 b) {
  return a.x * b.x + a.y * b.y + a.z * b.z + a.w * b.w;
}

// 64 blocks, 2 batch rows per block, 512 threads:
//   jj = tid & 127  -> owns gate rows {jj + 128*p, p=0..5}
//   kh = tid >> 7   -> quarter of the K dimension
__global__ __launch_bounds__(512) void decoder_kernel(
    const float* __restrict__ eh,
    const float* __restrict__ bih,
    const float* __restrict__ bhh,
    const float* __restrict__ bout,
    const float* __restrict__ ws,
    float* __restrict__ out) {
  __shared__ __align__(16) float xv[2 * NH];   // layer-0 input (feedback)
  __shared__ __align__(16) float h0s[2 * NH];  // layer-0 hidden
  __shared__ __align__(16) float h1s[2 * NH];  // layer-1 hidden
  __shared__ float red[3][128][25];            // k-split partials (25 = pad, odd stride)
  __shared__ float sbih[NL * G3];
  __shared__ float sbhh[NL * G3];
  __shared__ float sbout[NO];

  const int tid = threadIdx.x;
  const int jj = tid & 127;
  const int kh = tid >> 7;           // 0..3
  const int r0 = blockIdx.x * 2;     // batch rows r0, r0+1

  for (int i = tid; i < NL * G3; i += 512) { sbih[i] = bih[i]; sbhh[i] = bhh[i]; }
  for (int i = tid; i < NO; i += 512) sbout[i] = bout[i];
  for (int i = tid; i < 2 * NH; i += 512) {
    int r = i >> 8, k = i & 255;
    h0s[i] = eh[(size_t)(0 * NB + r0 + r) * NH + k];
    h1s[i] = eh[(size_t)(1 * NB + r0 + r) * NH + k];
    xv[i] = 0.f;
  }
  __syncthreads();

  const int k4beg = kh * 16;

  for (int t = 0; t < NT; ++t) {
    for (int l = 0; l < NL; ++l) {
      const float* xin = (l == 0) ? xv : h0s;
      float* hsrc = (l == 0) ? h0s : h1s;
      const float* Wi = ws + WIHT_OFF + l * 196608;
      const float* Wh = ws + WHHT_OFF + l * 196608;
      float acc[24];  // [r(2)][mat(2)][p(6)]
#pragma unroll
      for (int i = 0; i < 24; ++i) acc[i] = 0.f;
#pragma unroll 2
      for (int k4 = k4beg; k4 < k4beg + 16; ++k4) {
        const float4* wri = (const float4*)(Wi + k4 * 3072);
        const float4* wrh = (const float4*)(Wh + k4 * 3072);
        float4 xa = *(const float4*)(xin + k4 * 4);         // wave-uniform broadcast
        float4 xb = *(const float4*)(xin + NH + k4 * 4);
        float4 ha = *(const float4*)(hsrc + k4 * 4);
        float4 hb = *(const float4*)(hsrc + NH + k4 * 4);
#pragma unroll
        for (int p = 0; p < 6; ++p) {
          float4 wi = wri[jj + 128 * p];                    // coalesced 16B/lane
          float4 wh = wrh[jj + 128 * p];
          acc[0 * 12 + 0 * 6 + p] += dot4(wi, xa);
          acc[0 * 12 + 1 * 6 + p] += dot4(wh, ha);
          acc[1 * 12 + 0 * 6 + p] += dot4(wi, xb);
          acc[1 * 12 + 1 * 6 + p] += dot4(wh, hb);
        }
      }
      if (kh) {
#pragma unroll
        for (int i = 0; i < 24; ++i) red[kh - 1][jj][i] = acc[i];
      }
      __syncthreads();
      if (kh == 0) {
#pragma unroll
        for (int q = 0; q < 3; ++q)
#pragma unroll
          for (int i = 0; i < 24; ++i) acc[i] += red[q][jj][i];
#pragma unroll
        for (int e = 0; e < 2; ++e) {      // hidden element jj + 128*e
          int j0 = jj + 128 * e;
#pragma unroll
          for (int r = 0; r < 2; ++r) {
            // gate triple for element j0: r-gate p=e, z-gate p=e+2, n-gate p=e+4
            float gir = acc[r * 12 + e]     + sbih[l * G3 + j0];
            float giz = acc[r * 12 + e + 2] + sbih[l * G3 + 256 + j0];
            float gin = acc[r * 12 + e + 4] + sbih[l * G3 + 512 + j0];
            float ghr = acc[r * 12 + 6 + e]     + sbhh[l * G3 + j0];
            float ghz = acc[r * 12 + 6 + e + 2] + sbhh[l * G3 + 256 + j0];
            float ghn = acc[r * 12 + 6 + e + 4] + sbhh[l * G3 + 512 + j0];
            float rg = 1.f / (1.f + expf(-(gir + ghr)));
            float zg = 1.f / (1.f + expf(-(giz + ghz)));
            float ng = tanhf(gin + rg * ghn);
            float hold = hsrc[r * NH + j0];
            hsrc[r * NH + j0] = (1.f - zg) * ng + zg * hold;
          }
        }
      }
      __syncthreads();
    }
    // ---- output linear: out = h1 @ Wout^T + bout ; feedback x = out ----
    {
      const float* Wo = ws + WOUT_OFF;
      float oa[4];  // [p(2)][r(2)] : oa[p]=row0, oa[p+2]=row1
#pragma unroll
      for (int i = 0; i < 4; ++i) oa[i] = 0.f;
#pragma unroll 2
      for (int k4 = k4beg; k4 < k4beg + 16; ++k4) {
        const float4* wro = (const float4*)(Wo + k4 * 1024);
        float4 ha = *(const float4*)(h1s + k4 * 4);
        float4 hb = *(const float4*)(h1s + NH + k4 * 4);
#pragma unroll
        for (int p = 0; p < 2; ++p) {
          float4 w = wro[jj + 128 * p];
          oa[p] += dot4(w, ha);
          oa[p + 2] += dot4(w, hb);
        }
      }
      if (kh) {
#pragma unroll
        for (int i = 0; i < 4; ++i) red[kh - 1][jj][i] = oa[i];
      }
      __syncthreads();
      if (kh == 0) {
#pragma unroll
        for (int q = 0; q < 3; ++q)
#pragma unroll
          for (int i = 0; i < 4; ++i) oa[i] += red[q][jj][i];
#pragma unroll
        for (int p = 0; p < 2; ++p) {
          int o = jj + 128 * p;
          float v0 = oa[p] + sbout[o];
          float v1 = oa[p + 2] + sbout[o];
          out[((size_t)(r0 + 0) * NT + t) * NO + o] = v0;
          out[((size_t)(r0 + 1) * NT + t) * NO + o] = v1;
          xv[o] = v0;        // feedback (O == H, detach is a no-op in fwd)
          xv[NH + o] = v1;
        }
      }
      __syncthreads();
    }
  }
  // ---- h_final: [L,B,H] appended after decoder_outputs ----
  const size_t base = (size_t)NB * NT * NO;
  for (int i = tid; i < 2 * NH; i += 512) {
    int r = i >> 8, k = i & 255;
    out[base + (size_t)(0 * NB + r0 + r) * NH + k] = h0s[i];
    out[base + (size_t)(1 * NB + r0 + r) * NH + k] = h1s[i];
  }
}

extern "C" void kernel_launch(void* const* d_in, const int* in_sizes, int n_in,
                              void* d_out, int out_size, void* d_ws, size_t ws_size,
                              hipStream_t stream) {
  const float* eh   = (const float*)d_in[1];  // encoder_hidden [L,B,H]
  const float* Wih  = (const float*)d_in[2];  // [L,3H,H]
  const float* Whh  = (const float*)d_in[3];  // [L,3H,H]
  const float* bih  = (const float*)d_in[4];  // [L,3H]
  const float* bhh  = (const float*)d_in[5];  // [L,3H]
  const float* Wout = (const float*)d_in[6];  // [O,H]
  const float* bo   = (const float*)d_in[7];  // [O]
  float* ws  = (float*)d_ws;
  float* out = (float*)d_out;

  hipLaunchKernelGGL(prep_kernel, dim3(1536), dim3(256), 0, stream, Wih, Whh, Wout, ws);
  hipLaunchKernelGGL(decoder_kernel, dim3(64), dim3(512), 0, stream, eh, bih, bhh, bo, ws, out);
}

// Round 3
// 30059.122 us; speedup vs baseline: 1.1417x; 1.1417x over previous
//
#include <hip/hip_runtime.h>

#define NB 128
#define NT 1024
#define NH 256
#define NL 2
#define NO 256

// ws float layout:
//   Wih packed [l][k4][j][4]  at 0        (393216 floats)   = W_ih[l][j][4k4+c]
//   Whh packed [l][k4][j][4]  at 393216
//   Wout packed [k4][o][4]    at 786432   (65536)
//   xslot  [par2][g64][r2][256] at 851968 (65536)
//   h0slot                      at 917504
//   h1slot                      at 983040
//   flags (ints) [ph3][par2][g64][s4] at int-index 1048576 (1536 ints)
#define WIHT_OFF 0
#define WHHT_OFF 393216
#define WOUT_OFF 786432
#define XSLOT_OFF 851968
#define H0SLOT_OFF 917504
#define H1SLOT_OFF 983040
#define FLAG_OFF 1048576

__global__ void prep_kernel(const float* __restrict__ Wih,
                            const float* __restrict__ Whh,
                            const float* __restrict__ Wout,
                            float* __restrict__ ws) {
  int idx = blockIdx.x * 256 + threadIdx.x;
  if (idx < 393216) {
    int c = idx & 3;
    int q = idx >> 2;
    int j = q % 768;
    int lk4 = q / 768;
    int k4 = lk4 & 63;
    int l = lk4 >> 6;
    size_t src = (size_t)(l * 768 + j) * 256 + k4 * 4 + c;
    ws[WIHT_OFF + idx] = Wih[src];
    ws[WHHT_OFF + idx] = Whh[src];
  }
  if (idx < 65536) {
    int c = idx & 3;
    int q = idx >> 2;
    int o = q & 255;
    int k4 = q >> 8;
    ws[WOUT_OFF + idx] = Wout[o * 256 + k4 * 4 + c];
  }
  if (idx < 1536) {
    int* flags = (int*)ws + FLAG_OFF;
    // LLC-coherent zero: decoder polls these with agent-scope atomics.
    __hip_atomic_store(&flags[idx], 0, __ATOMIC_RELAXED, __HIP_MEMORY_SCOPE_AGENT);
  }
}

__device__ __forceinline__ float dot4(float4 a, float4 b) {
  return a.x * b.x + a.y * b.y + a.z * b.z + a.w * b.w;
}

// 256 blocks = 64 batch-pairs (g) x 4 hidden slices (s). Block (g,s) owns
// hidden elems [64s,64s+64) of both layers + out rows [64s,64s+64), for batch
// rows {2g, 2g+1}. Per step it reads only its 192+192+64 weight rows
// (0.85 MB/CU/step vs 3.4 MB unsplit -> beats the per-CU L1 stream floor).
// Siblings exchange 64-element slices via LLC (relaxed agent atomics + flags).
// 1024 threads: jj = tid&63 (hidden elem), kh = tid>>6 (16-way K split).
__global__ __launch_bounds__(1024) void decoder_kernel(
    const float* __restrict__ eh,
    const float* __restrict__ bih,
    const float* __restrict__ bhh,
    const float* __restrict__ bout,
    float* __restrict__ ws,
    float* __restrict__ out) {
  __shared__ float red[16 * 832];           // [kh][jj*13+i] partials, 53 KB
  __shared__ __align__(16) float xs[2 * NH];
  __shared__ __align__(16) float h0s[2 * NH];
  __shared__ __align__(16) float h1s[2 * NH];
  __shared__ float sbias[NL * 2 * 3 * 64];  // (l*6+mat*3+gate)*64+jj
  __shared__ float sbo[64];

  const int tid = threadIdx.x;
  const int b = blockIdx.x;
  const int s = (b & 7) >> 1;                 // slice: constant per XCD (if %8 rr)
  const int g = (b >> 3) + ((b & 1) << 5);    // batch pair
  const int r0 = g * 2;
  const int jj = tid & 63;
  const int kh = tid >> 6;                    // 0..15
  const int hj = s * 64 + jj;                 // owned hidden element

  float* const xslot = ws + XSLOT_OFF;
  float* const h0slot = ws + H0SLOT_OFF;
  float* const h1slot = ws + H1SLOT_OFF;
  int* const flags = (int*)ws + FLAG_OFF;

  if (tid < 768) {
    int q = tid >> 6;                 // q = l*6 + mat*3 + gate
    int gate = q % 3, mat = (q / 3) & 1, l = q / 6;
    const float* bsrc = mat ? bhh : bih;
    sbias[tid] = bsrc[l * 768 + gate * 256 + hj];
  }
  if (tid < 64) sbo[tid] = bout[hj];
  for (int i = tid; i < 2 * NH; i += 1024) {
    int r = i >> 8, k = i & 255;
    h0s[i] = eh[(size_t)(r0 + r) * NH + k];
    h1s[i] = eh[(size_t)(NB + r0 + r) * NH + k];
    xs[i] = 0.f;
  }
  __syncthreads();

#define WAIT_FLAGS(PH, PARV, TGT)                                              \
  if (tid < 4 && tid != s) {                                                   \
    const int fidx = (((PH)*2 + (PARV)) * 64 + g) * 4 + tid;                   \
    while (__hip_atomic_load(&flags[fidx], __ATOMIC_RELAXED,                   \
                             __HIP_MEMORY_SCOPE_AGENT) < (TGT))                \
      __builtin_amdgcn_s_sleep(2);                                             \
  }                                                                            \
  __syncthreads();

#define LOAD_FULL(DST, SLOT, PARV)                                             \
  if (tid < 2 * NH) {                                                          \
    (DST)[tid] = __hip_atomic_load(&(SLOT)[((PARV)*64 + g) * (2 * NH) + tid],  \
                                   __ATOMIC_RELAXED, __HIP_MEMORY_SCOPE_AGENT);\
  }                                                                            \
  __syncthreads();

#define GRU_PHASE(L, XIN, HVEC, SLOT, PH)                                      \
  {                                                                            \
    const float4* Wi = (const float4*)(ws + WIHT_OFF + (L)*196608);            \
    const float4* Wh = (const float4*)(ws + WHHT_OFF + (L)*196608);            \
    float acc[12]; /* [r*6 + mat*3 + gate] */                                  \
    _Pragma("unroll") for (int i = 0; i < 12; ++i) acc[i] = 0.f;               \
    _Pragma("unroll") for (int kq = 0; kq < 4; ++kq) {                         \
      const int k4 = (kh << 2) + kq;                                           \
      const float4* wi = Wi + k4 * 768 + hj;                                   \
      const float4* wh = Wh + k4 * 768 + hj;                                   \
      float4 xa = *(const float4*)((XIN) + k4 * 4);                            \
      float4 xb = *(const float4*)((XIN) + NH + k4 * 4);                       \
      float4 ha = *(const float4*)((HVEC) + k4 * 4);                           \
      float4 hb = *(const float4*)((HVEC) + NH + k4 * 4);                      \
      _Pragma("unroll") for (int gate = 0; gate < 3; ++gate) {                 \
        float4 wiv = wi[gate * 256];                                           \
        float4 whv = wh[gate * 256];                                           \
        acc[0 + gate] += dot4(wiv, xa);                                        \
        acc[3 + gate] += dot4(whv, ha);                                        \
        acc[6 + gate] += dot4(wiv, xb);                                        \
        acc[9 + gate] += dot4(whv, hb);                                        \
      }                                                                        \
    }                                                                          \
    _Pragma("unroll") for (int i = 0; i < 12; ++i)                             \
        red[kh * 832 + jj * 13 + i] = acc[i];                                  \
    __syncthreads();                                                           \
    float tot = 0.f;                                                           \
    if (kh < 12) {                                                             \
      _Pragma("unroll") for (int q = 0; q < 16; ++q)                           \
          tot += red[q * 832 + jj * 13 + kh];                                  \
    }                                                                          \
    __syncthreads();                                                           \
    if (kh < 12) red[jj * 13 + kh] = tot;                                      \
    __syncthreads();                                                           \
    if (kh < 2) {                                                              \
      const int r = kh;                                                        \
      float gir = red[jj * 13 + r * 6 + 0] + sbias[((L)*6 + 0) * 64 + jj];     \
      float giz = red[jj * 13 + r * 6 + 1] + sbias[((L)*6 + 1) * 64 + jj];     \
      float gin = red[jj * 13 + r * 6 + 2] + sbias[((L)*6 + 2) * 64 + jj];     \
      float ghr = red[jj * 13 + r * 6 + 3] + sbias[((L)*6 + 3) * 64 + jj];     \
      float ghz = red[jj * 13 + r * 6 + 4] + sbias[((L)*6 + 4) * 64 + jj];     \
      float ghn = red[jj * 13 + r * 6 + 5] + sbias[((L)*6 + 5) * 64 + jj];     \
      float rg = 1.f / (1.f + expf(-(gir + ghr)));                             \
      float zg = 1.f / (1.f + expf(-(giz + ghz)));                             \
      float ng = tanhf(gin + rg * ghn);                                        \
      float hold = (HVEC)[r * NH + hj];                                        \
      float hnew = (1.f - zg) * ng + zg * hold;                                \
      __hip_atomic_store(&(SLOT)[((par * 64 + g) * 2 + r) * NH + hj], hnew,    \
                         __ATOMIC_RELAXED, __HIP_MEMORY_SCOPE_AGENT);          \
    }                                                                          \
    asm volatile("s_waitcnt vmcnt(0)" ::: "memory");                           \
    __syncthreads();                                                           \
    if (tid == 0)                                                              \
      __hip_atomic_store(&flags[(((PH)*2 + par) * 64 + g) * 4 + s], t + 1,     \
                         __ATOMIC_RELAXED, __HIP_MEMORY_SCOPE_AGENT);          \
  }

  for (int t = 0; t < NT; ++t) {
    const int par = t & 1;
    // ---- phase A: layer-0 GRU (needs x_t from C(t-1); h0_{t-1} is in LDS) --
    if (t > 0) {
      WAIT_FLAGS(2, par ^ 1, t);
      LOAD_FULL(xs, xslot, par ^ 1);
    }
    GRU_PHASE(0, xs, h0s, h0slot, 0);
    // ---- phase B: layer-1 GRU (needs full h0_t; h1_{t-1} is in LDS) -------
    WAIT_FLAGS(0, par, t + 1);
    LOAD_FULL(h0s, h0slot, par);
    GRU_PHASE(1, h0s, h1s, h1slot, 1);
    // ---- phase C: out linear (needs full h1_t); publish x_{t+1} -----------
    WAIT_FLAGS(1, par, t + 1);
    LOAD_FULL(h1s, h1slot, par);
    {
      const float4* Wo = (const float4*)(ws + WOUT_OFF);
      float o0 = 0.f, o1 = 0.f;
#pragma unroll
      for (int kq = 0; kq < 4; ++kq) {
        const int k4 = (kh << 2) + kq;
        float4 w = Wo[k4 * 256 + hj];
        float4 ha = *(const float4*)(h1s + k4 * 4);
        float4 hb = *(const float4*)(h1s + NH + k4 * 4);
        o0 += dot4(w, ha);
        o1 += dot4(w, hb);
      }
      red[kh * 832 + jj * 13 + 0] = o0;
      red[kh * 832 + jj * 13 + 1] = o1;
      __syncthreads();
      if (kh < 2) {
        const int r = kh;
        float tot = 0.f;
#pragma unroll
        for (int q = 0; q < 16; ++q) tot += red[q * 832 + jj * 13 + r];
        float v = tot + sbo[jj];
        out[((size_t)(r0 + r) * NT + t) * NO + hj] = v;
        __hip_atomic_store(&xslot[((par * 64 + g) * 2 + r) * NH + hj], v,
                           __ATOMIC_RELAXED, __HIP_MEMORY_SCOPE_AGENT);
      }
      asm volatile("s_waitcnt vmcnt(0)" ::: "memory");
      __syncthreads();
      if (tid == 0)
        __hip_atomic_store(&flags[((2 * 2 + par) * 64 + g) * 4 + s], t + 1,
                           __ATOMIC_RELAXED, __HIP_MEMORY_SCOPE_AGENT);
    }
  }

  // ---- h_final [L,B,H]: each block writes its own slice ----
  if (tid < 128) {
    const int r = tid >> 6;
    const size_t base = (size_t)NB * NT * NO;
    out[base + (size_t)(r0 + r) * NH + hj] = h0s[r * NH + hj];
    out[base + (size_t)(NB + r0 + r) * NH + hj] = h1s[r * NH + hj];
  }
#undef WAIT_FLAGS
#undef LOAD_FULL
#undef GRU_PHASE
}

extern "C" void kernel_launch(void* const* d_in, const int* in_sizes, int n_in,
                              void* d_out, int out_size, void* d_ws, size_t ws_size,
                              hipStream_t stream) {
  const float* eh   = (const float*)d_in[1];
  const float* Wih  = (const float*)d_in[2];
  const float* Whh  = (const float*)d_in[3];
  const float* bih  = (const float*)d_in[4];
  const float* bhh  = (const float*)d_in[5];
  const float* Wout = (const float*)d_in[6];
  const float* bo   = (const float*)d_in[7];
  float* ws  = (float*)d_ws;
  float* out = (float*)d_out;

  hipLaunchKernelGGL(prep_kernel, dim3(1536), dim3(256), 0, stream, Wih, Whh, Wout, ws);
  hipLaunchKernelGGL(decoder_kernel, dim3(256), dim3(1024), 0, stream,
                     eh, bih, bhh, bo, ws, out);
}